// Round 8
// baseline (280.911 us; speedup 1.0000x reference)
//
#include <hip/hip_runtime.h>

typedef unsigned short u16;
typedef unsigned int   u32;
typedef float f32x4 __attribute__((ext_vector_type(4)));
typedef u32   u32x4 __attribute__((ext_vector_type(4)));
typedef u16   u16x4 __attribute__((ext_vector_type(4)));
typedef u16   u16x8 __attribute__((ext_vector_type(8)));
typedef __bf16 bf16x8 __attribute__((ext_vector_type(8)));

// ---------------- workspace byte offsets ----------
#define OFF_X    0x0000000ULL
#define OFF_WQ   0x0400000ULL
#define OFF_WO   0x0460000ULL
#define OFF_W1   0x0480000ULL
#define OFF_W2   0x0500000ULL
#define OFF_Q    0x0580000ULL
#define OFF_K    0x0980000ULL
#define OFF_VT   0x0D80000ULL
#define OFF_CTX  0x1180000ULL

__device__ __forceinline__ u16 f2bf(float f){
  u32 u = __float_as_uint(f);
  return (u16)((u + 0x7FFFu + ((u >> 16) & 1u)) >> 16);
}
__device__ __forceinline__ u32 cvt_pk(float lo, float hi){
  u32 r;
  asm volatile("v_cvt_pk_bf16_f32 %0, %1, %2" : "=v"(r) : "v"(lo), "v"(hi));
  return r;
}
__device__ __forceinline__ bf16x8 ld_bf8(const u16* p){
  return *(const bf16x8*)p;
}
__device__ __forceinline__ bf16x8 lds_bf8(const u16* p){
  return *(const bf16x8*)p;
}
__device__ __forceinline__ f32x4 ntld4(const float* p){
  return __builtin_nontemporal_load((const f32x4*)p);
}
__device__ __forceinline__ float ntld(const float* p){
  return __builtin_nontemporal_load(p);
}
__device__ __forceinline__ f32x4 MFMA(bf16x8 a, bf16x8 b, f32x4 c){
  return __builtin_amdgcn_mfma_f32_16x16x32_bf16(a, b, c, 0, 0, 0);
}
// barrier WITHOUT the vmcnt(0) drain: only LDS writes must be visible.
__device__ __forceinline__ void lbar(){
  asm volatile("s_waitcnt lgkmcnt(0)" ::: "memory");
  __builtin_amdgcn_s_barrier();
}
template<int C>
__device__ __forceinline__ float dpp_rot(float x){
  int i = __float_as_int(x);
  return __int_as_float(__builtin_amdgcn_update_dpp(i, i, C, 0xF, 0xF, false));
}
__device__ __forceinline__ float rmax16(float x){
  x = fmaxf(x, dpp_rot<0x121>(x)); x = fmaxf(x, dpp_rot<0x122>(x));
  x = fmaxf(x, dpp_rot<0x124>(x)); x = fmaxf(x, dpp_rot<0x128>(x));
  return x;
}
__device__ __forceinline__ float rsum16(float x){
  x += dpp_rot<0x121>(x); x += dpp_rot<0x122>(x);
  x += dpp_rot<0x124>(x); x += dpp_rot<0x128>(x);
  return x;
}

// ---------------- kernel 0: convert x + all weights to bf16 (x4 vectorized) ---
__global__ __launch_bounds__(256) void prep_kernel(
    const float* __restrict__ x,  const float* __restrict__ Wq,
    const float* __restrict__ Wk, const float* __restrict__ Wv,
    const float* __restrict__ Wo, const float* __restrict__ W1,
    const float* __restrict__ W2, u16* __restrict__ dst)
{
  int i = (blockIdx.x * 256 + threadIdx.x) * 4;   // grid 2816 -> exactly 2883584
  const float* src;
  int off;
  if (i < 2097152){ src = x; off = i; }
  else {
    int j = i - 2097152;
    if      (j <  65536){ src = Wq; off = j; }
    else if (j < 131072){ src = Wk; off = j -  65536; }
    else if (j < 196608){ src = Wv; off = j - 131072; }
    else if (j < 262144){ src = Wo; off = j - 196608; }
    else if (j < 524288){ src = W1; off = j - 262144; }
    else                { src = W2; off = j - 524288; }
  }
  f32x4 v = *(const f32x4*)(src + off);
  u16x4 o;
  o[0] = f2bf(v[0]); o[1] = f2bf(v[1]); o[2] = f2bf(v[2]); o[3] = f2bf(v[3]);
  *(u16x4*)(dst + i) = o;
}

// ---------------- kernel 1: QKV projection ------------------------------------
__global__ __launch_bounds__(512) void qkv_kernel(
    const u16* __restrict__ X, const u16* __restrict__ W3,
    const float* __restrict__ bq, const float* __restrict__ bk,
    const float* __restrict__ bv,
    u16* __restrict__ Q, u16* __restrict__ K, u16* __restrict__ VT)
{
  __shared__ u16 vtile[32][264];
  const int tid = threadIdx.x;
  const int lane = tid & 63, w = tid >> 6;
  const int g = lane >> 4, c = lane & 15;
  const int m0 = blockIdx.x * 32;
  const int nb = blockIdx.y;
  const u16* Wb = W3 + nb * 65536;
  const float* bias = (nb == 0) ? bq : ((nb == 1) ? bk : bv);
  const int n0 = w * 32;

  f32x4 acc[2][2];
  #pragma unroll
  for (int i = 0; i < 2; ++i)
    #pragma unroll
    for (int j = 0; j < 2; ++j){ f32x4 z = {0.f,0.f,0.f,0.f}; acc[i][j] = z; }

  #pragma unroll
  for (int kt = 0; kt < 8; ++kt){
    bf16x8 a0 = ld_bf8(X  + (size_t)(m0 +      c) * 256 + kt*32 + g*8);
    bf16x8 a1 = ld_bf8(X  + (size_t)(m0 + 16 + c) * 256 + kt*32 + g*8);
    bf16x8 b0 = ld_bf8(Wb + (size_t)(n0 +      c) * 256 + kt*32 + g*8);
    bf16x8 b1 = ld_bf8(Wb + (size_t)(n0 + 16 + c) * 256 + kt*32 + g*8);
    acc[0][0] = MFMA(a0, b0, acc[0][0]);
    acc[0][1] = MFMA(a0, b1, acc[0][1]);
    acc[1][0] = MFMA(a1, b0, acc[1][0]);
    acc[1][1] = MFMA(a1, b1, acc[1][1]);
  }

  const int bi = m0 >> 11, tbase = m0 & 2047;

  if (nb == 2){
    #pragma unroll
    for (int qt = 0; qt < 2; ++qt)
    #pragma unroll
    for (int nt = 0; nt < 2; ++nt)
    #pragma unroll
    for (int r = 0; r < 4; ++r){
      int row = qt*16 + g*4 + r;
      int col = n0 + nt*16 + c;
      vtile[row][col] = f2bf(acc[qt][nt][r] + bias[col]);
    }
    __syncthreads();
    #pragma unroll
    for (int s = 0; s < 2; ++s){
      int u = tid*2 + s;              // 0..1023
      int h = u >> 7, d = (u >> 2) & 31, sl0 = (u & 3) * 8;
      u16x8 o;
      #pragma unroll
      for (int jj = 0; jj < 8; ++jj){
        int sl = sl0 + jj;
        int tt = (sl >> 1) + ((sl & 1) << 4);   // stored slot sl holds t-offset
        o[jj] = vtile[tt][h*32 + d];
      }
      *(u16x8*)(VT + ((size_t)(bi*8 + h) * 32 + d) * 2048 + tbase + sl0) = o;
    }
  } else {
    #pragma unroll
    for (int qt = 0; qt < 2; ++qt)
    #pragma unroll
    for (int nt = 0; nt < 2; ++nt)
    #pragma unroll
    for (int r = 0; r < 4; ++r){
      int mrow = m0 + qt*16 + g*4 + r;
      int col  = n0 + nt*16 + c;
      float v = acc[qt][nt][r] + bias[col];
      int t = mrow & 2047;
      int h = col >> 5, d = col & 31;
      u16 hv = f2bf(v);
      if (nb == 0) Q[((size_t)(bi*8 + h) * 2048 + t) * 32 + d] = hv;
      else         K[((size_t)(bi*8 + h) * 2048 + t) * 32 + d] = hv;
    }
  }
}

// ---------------- kernel 2: fused flash attention with pos bias ---------------
// R6 geometry (512 WGs XCD-swizzled, 16 q-rows, 8 waves = 8 heads, 64-k tiles,
// packed bf16 bias double-buffered). NEW: TWO pos/pad staging register sets ->
// each set has 2 full tiles between issue and consume, and the lgkm-only
// barrier keeps those loads in flight. K prefetch dropped (L2-resident,
// issued at tile top) to fund the +20 VGPR for the second set.
__global__ __launch_bounds__(512, 4) void attn_kernel(
    const float* __restrict__ pos, const float* __restrict__ pad,
    const u16* __restrict__ Q, const u16* __restrict__ K,
    const u16* __restrict__ VT, u16* __restrict__ ctx)
{
  __shared__ u32 bias_lds[2][4608];   // [buf][h*576 + qr*36 + col]
  __shared__ u32 p_lds[8][16][34];

  const int tid = threadIdx.x;
  const int lane = tid & 63, w = tid >> 6;
  const int g = lane >> 4, c = lane & 15;
  const int bid = blockIdx.x;
  const int xcd = bid & 7;
  const int b = xcd >> 1;
  const int qtile = ((bid >> 3) << 1) | (xcd & 1);
  const int q0 = qtile * 16;

  const u16* Qb  = Q  + ((size_t)(b*8 + w) * 2048 + q0) * 32;
  const u16* Kb  = K  +  (size_t)(b*8 + w) * 2048 * 32;
  const u16* VTb = VT +  (size_t)(b*8 + w) * 32 * 2048;

  const float c1 = 1.4426950408889634f * 0.17677669529663689f; // log2e / sqrt(32)
  const float c2 = 1.4426950408889634f;                        // log2e

  bf16x8 qf = ld_bf8(Qb + (size_t)c * 32 + g*8);

  f32x4 O[2];
  { f32x4 z = {0.f,0.f,0.f,0.f}; O[0] = z; O[1] = z; }
  float m_[4], l_[4];
  #pragma unroll
  for (int r = 0; r < 4; ++r){ m_[r] = -3.0e38f; l_[r] = 0.f; }

  const int li = (lane >> 1) & 15;
  const int ls = lane >> 5;
  const int h0 = (lane & 1) * 4;

  // two named staging sets; each issued 2 tiles before consumption
  f32x4 fa0[2], fb0[2], fa1[2], fb1[2];
  float pa0[2], pb0[2], pa1[2], pb1[2];
  bf16x8 kf[4], vf[4];

  auto stage_load = [&](f32x4 (&FA)[2], f32x4 (&FB)[2],
                        float (&PA)[2], float (&PB)[2], int k0){
    #pragma unroll
    for (int j = 0; j < 2; ++j){
      int qr = w*2 + j;
      int k1 = ls*32 + li;
      const float* pr = pos + ((size_t)(b*2048 + q0 + qr) * 2048 + k0) * 8 + h0;
      FA[j] = ntld4(pr + (size_t)k1 * 8);
      FB[j] = ntld4(pr + (size_t)(k1 + 16) * 8);
      const float* dr = pad + (size_t)(b*2048 + q0 + qr) * 2048 + k0 + k1;
      PA[j] = ntld(dr);
      PB[j] = ntld(dr + 16);
    }
  };
  auto stage_write = [&](f32x4 (&FA)[2], f32x4 (&FB)[2],
                         float (&PA)[2], float (&PB)[2], int buf){
    u32* bl = &bias_lds[buf][0];
    #pragma unroll
    for (int j = 0; j < 2; ++j){
      int qr = w*2 + j;
      float plo = PA[j] * c2, phi = PB[j] * c2;
      int base = qr*36 + ls*16 + li;
      #pragma unroll
      for (int j2 = 0; j2 < 4; ++j2){
        float lo = fmaf(FA[j][j2], c1, plo);
        float hi = fmaf(FB[j][j2], c1, phi);
        bl[(h0 + j2)*576 + base] = cvt_pk(lo, hi);
      }
    }
  };
  auto load_vk = [&](int k0){
    vf[0] = ld_bf8(VTb + (size_t)(     c) * 2048 + k0      + g*8);
    vf[1] = ld_bf8(VTb + (size_t)(16 + c) * 2048 + k0      + g*8);
    vf[2] = ld_bf8(VTb + (size_t)(     c) * 2048 + k0 + 32 + g*8);
    vf[3] = ld_bf8(VTb + (size_t)(16 + c) * 2048 + k0 + 32 + g*8);
    kf[0] = ld_bf8(Kb + (size_t)(k0 +      c) * 32 + g*8);
    kf[1] = ld_bf8(Kb + (size_t)(k0 + 16 + c) * 32 + g*8);
    kf[2] = ld_bf8(Kb + (size_t)(k0 + 32 + c) * 32 + g*8);
    kf[3] = ld_bf8(Kb + (size_t)(k0 + 48 + c) * 32 + g*8);
  };

  auto body = [&](int t, f32x4 (&FA)[2], f32x4 (&FB)[2],
                  float (&PA)[2], float (&PB)[2]){
    const int k0 = t * 64;
    // 1. V + K for this tile (L2-resident; consumed after ~200+ cyc)
    load_vk(k0);
    // 2. commit bias(t+1) from the set loaded two tiles ago
    if (t < 31) stage_write(FA, FB, PA, PB, (t + 1) & 1);
    // 3. refill the same set with pos/pad(t+3) — 2 tiles of slack, and the
    //    lgkm-only barrier below keeps these in flight across tiles
    if (t <= 28) stage_load(FA, FB, PA, PB, k0 + 192);

    // 4. QK^T for all 64 k (waits K; V is older so it lands with it)
    f32x4 sS[4];
    {
      f32x4 z = {0.f,0.f,0.f,0.f};
      sS[0] = MFMA(qf, kf[0], z);
      sS[1] = MFMA(qf, kf[1], z);
      sS[2] = MFMA(qf, kf[2], z);
      sS[3] = MFMA(qf, kf[3], z);
    }

    // 5. merged softmax over 64 k per row
    const u32* blc = &bias_lds[t & 1][w*576];
    #pragma unroll
    for (int r = 0; r < 4; ++r){
      int rowb = (g*4 + r)*36;
      u32 dwA = blc[rowb + c];
      u32 dwB = blc[rowb + 16 + c];
      float v0 = fmaf(sS[0][r], c1, __uint_as_float(dwA << 16));
      float v1 = fmaf(sS[1][r], c1, __uint_as_float(dwA & 0xFFFF0000u));
      float v2 = fmaf(sS[2][r], c1, __uint_as_float(dwB << 16));
      float v3 = fmaf(sS[3][r], c1, __uint_as_float(dwB & 0xFFFF0000u));
      float mx = rmax16(fmaxf(fmaxf(v0, v1), fmaxf(v2, v3)));
      float mo = m_[r];
      float mn = fmaxf(mo, mx);
      float alpha = exp2f(mo - mn);
      m_[r] = mn;
      float p0 = exp2f(v0 - mn);
      float p1 = exp2f(v1 - mn);
      float p2 = exp2f(v2 - mn);
      float p3 = exp2f(v3 - mn);
      float ps = rsum16((p0 + p1) + (p2 + p3));
      l_[r] = l_[r] * alpha + ps;
      O[0][r] *= alpha;
      O[1][r] *= alpha;
      p_lds[w][g*4 + r][c]      = cvt_pk(p0, p1);
      p_lds[w][g*4 + r][16 + c] = cvt_pk(p2, p3);
    }

    // 6. PV: P as A-fragments (per-wave LDS transpose), V as B
    {
      u32x4 t0 = { p_lds[w][c][g*4 + 0], p_lds[w][c][g*4 + 1],
                   p_lds[w][c][g*4 + 2], p_lds[w][c][g*4 + 3] };
      u32x4 t1 = { p_lds[w][c][16 + g*4 + 0], p_lds[w][c][16 + g*4 + 1],
                   p_lds[w][c][16 + g*4 + 2], p_lds[w][c][16 + g*4 + 3] };
      bf16x8 pa0v = __builtin_bit_cast(bf16x8, t0);
      bf16x8 pa1v = __builtin_bit_cast(bf16x8, t1);
      O[0] = MFMA(pa0v, vf[0], O[0]);
      O[1] = MFMA(pa0v, vf[1], O[1]);
      O[0] = MFMA(pa1v, vf[2], O[0]);
      O[1] = MFMA(pa1v, vf[3], O[1]);
    }

    // 7. barrier: lgkmcnt(0) only — pos(t+3) global loads stay in flight
    lbar();
  };

  // prologue: S0<-tile0, write bias0 (drains only S0), S1<-tile1, S0<-tile2
  stage_load(fa0, fb0, pa0, pb0, 0);
  stage_write(fa0, fb0, pa0, pb0, 0);
  stage_load(fa1, fb1, pa1, pb1, 64);
  stage_load(fa0, fb0, pa0, pb0, 128);
  lbar();

  for (int tp = 0; tp < 16; ++tp){
    body(tp*2,     fa1, fb1, pa1, pb1);   // writes odd tile t+1 from set1
    body(tp*2 + 1, fa0, fb0, pa0, pb0);   // writes even tile t+1 from set0
  }

  // epilogue: normalize and store ctx (B*T, 256) bf16
  #pragma unroll
  for (int r = 0; r < 4; ++r){
    float inv = 1.0f / l_[r];
    int q = q0 + g*4 + r;
    size_t base = (size_t)(b*2048 + q) * 256 + w*32;
    ctx[base +      c] = f2bf(O[0][r] * inv);
    ctx[base + 16 + c] = f2bf(O[1][r] * inv);
  }
}

// ---------------- kernel 3: fused tail: Wo+LN1 -> FFN1+LeakyReLU -> FFN2+LN2 --
__global__ __launch_bounds__(512, 2) void tail_kernel(
    const u16* __restrict__ ctx, const u16* __restrict__ Wo,
    const float* __restrict__ bo, const float* __restrict__ x,
    const float* __restrict__ g1, const float* __restrict__ be1,
    const u16* __restrict__ W1, const float* __restrict__ b1,
    const u16* __restrict__ W2, const float* __restrict__ b2,
    const float* __restrict__ g2, const float* __restrict__ be2,
    float* __restrict__ out)
{
  __shared__ u16 x1t[32*256];     // 16 KB
  __shared__ u16 ht[32*512];      // 32 KB (one 512-col half of h)
  __shared__ float sm1[32][8], sm2[32][8];

  const int tid = threadIdx.x;
  const int lane = tid & 63, w = tid >> 6;
  const int g = lane >> 4, c = lane & 15;
  const int m0 = blockIdx.x * 32;
  const int n0 = w * 32;

  // ---- phase A: Wo GEMM (K=256) + bias + residual + LN1 ----
  f32x4 acc[2][2];
  #pragma unroll
  for (int i = 0; i < 2; ++i)
    #pragma unroll
    for (int j = 0; j < 2; ++j){ f32x4 z = {0.f,0.f,0.f,0.f}; acc[i][j] = z; }

  #pragma unroll
  for (int kt = 0; kt < 8; ++kt){
    bf16x8 a0 = ld_bf8(ctx + (size_t)(m0 +      c) * 256 + kt*32 + g*8);
    bf16x8 a1 = ld_bf8(ctx + (size_t)(m0 + 16 + c) * 256 + kt*32 + g*8);
    bf16x8 b0 = ld_bf8(Wo  + (size_t)(n0 +      c) * 256 + kt*32 + g*8);
    bf16x8 b1v= ld_bf8(Wo  + (size_t)(n0 + 16 + c) * 256 + kt*32 + g*8);
    acc[0][0] = MFMA(a0, b0, acc[0][0]);
    acc[0][1] = MFMA(a0, b1v, acc[0][1]);
    acc[1][0] = MFMA(a1, b0, acc[1][0]);
    acc[1][1] = MFMA(a1, b1v, acc[1][1]);
  }

  float val[2][2][4];
  #pragma unroll
  for (int qt = 0; qt < 2; ++qt)
  #pragma unroll
  for (int nt = 0; nt < 2; ++nt)
  #pragma unroll
  for (int r = 0; r < 4; ++r){
    int mrow = m0 + qt*16 + g*4 + r;
    int col  = n0 + nt*16 + c;
    val[qt][nt][r] = acc[qt][nt][r] + bo[col] + x[(size_t)mrow*256 + col];
  }

  #pragma unroll
  for (int qt = 0; qt < 2; ++qt)
  #pragma unroll
  for (int r = 0; r < 4; ++r){
    float v0 = val[qt][0][r], v1 = val[qt][1][r];
    float p1 = rsum16(v0 + v1);
    float p2 = rsum16(v0*v0 + v1*v1);
    if (c == 0){
      int rr = qt*16 + g*4 + r;
      sm1[rr][w] = p1; sm2[rr][w] = p2;
    }
  }
  __syncthreads();  // #1

  float yv[2][2][4];   // LN1 output, kept as LN2 residual
  #pragma unroll
  for (int qt = 0; qt < 2; ++qt)
  #pragma unroll
  for (int r = 0; r < 4; ++r){
    int rr = qt*16 + g*4 + r;
    float S1 = 0.f, S2 = 0.f;
    #pragma unroll
    for (int j = 0; j < 8; ++j){ S1 += sm1[rr][j]; S2 += sm2[rr][j]; }
    float mean = S1 * (1.0f/256.0f);
    float var  = S2 * (1.0f/256.0f) - mean*mean;
    float rstd = rsqrtf(var + 1e-5f);
    #pragma unroll
    for (int nt = 0; nt < 2; ++nt){
      int col = n0 + nt*16 + c;
      float y = (val[qt][nt][r] - mean) * rstd * g1[col] + be1[col];
      yv[qt][nt][r] = y;
      int elem = rr*256 + col;
      x1t[elem ^ ((rr & 7) << 3)] = f2bf(y);
    }
  }
  __syncthreads();  // #2: x1t visible

  f32x4 acc3[2][2];
  #pragma unroll
  for (int i = 0; i < 2; ++i)
    #pragma unroll
    for (int j = 0; j < 2; ++j){ f32x4 z = {0.f,0.f,0.f,0.f}; acc3[i][j] = z; }

  #pragma unroll
  for (int half = 0; half < 2; ++half){
    // ---- phase B: FFN1 for cols [half*512, half*512+512) + LeakyReLU -> ht ----
    #pragma unroll
    for (int ns = 0; ns < 2; ++ns){
      const int ncol = half*512 + w*64 + ns*32;   // global h col base
      f32x4 acc2[2][2];
      #pragma unroll
      for (int i = 0; i < 2; ++i)
        #pragma unroll
        for (int j = 0; j < 2; ++j){ f32x4 z = {0.f,0.f,0.f,0.f}; acc2[i][j] = z; }
      #pragma unroll
      for (int kt = 0; kt < 8; ++kt){
        int e0 = (     c)*256 + kt*32 + g*8;
        int e1 = (16 + c)*256 + kt*32 + g*8;
        bf16x8 a0 = lds_bf8(x1t + (e0 ^ ((c & 7) << 3)));
        bf16x8 a1 = lds_bf8(x1t + (e1 ^ (((16 + c) & 7) << 3)));
        bf16x8 b0 = ld_bf8(W1 + (size_t)(ncol +      c) * 256 + kt*32 + g*8);
        bf16x8 b1v= ld_bf8(W1 + (size_t)(ncol + 16 + c) * 256 + kt*32 + g*8);
        acc2[0][0] = MFMA(a0, b0, acc2[0][0]);
        acc2[0][1] = MFMA(a0, b1v, acc2[0][1]);
        acc2[1][0] = MFMA(a1, b0, acc2[1][0]);
        acc2[1][1] = MFMA(a1, b1v, acc2[1][1]);
      }
      #pragma unroll
      for (int qt = 0; qt < 2; ++qt)
      #pragma unroll
      for (int nt = 0; nt < 2; ++nt)
      #pragma unroll
      for (int r = 0; r < 4; ++r){
        int row = qt*16 + g*4 + r;
        int gcol = ncol + nt*16 + c;
        float v = acc2[qt][nt][r] + b1[gcol];
        v = (v >= 0.f) ? v : v * 0.01f;
        int elem = row*512 + (gcol - half*512);
        ht[elem ^ ((row & 7) << 3)] = f2bf(v);
      }
    }
    __syncthreads();  // ht ready

    // ---- phase C: FFN2 partial K (512 cols of this half) ----
    #pragma unroll
    for (int kt = 0; kt < 16; ++kt){
      int e0 = (     c)*512 + kt*32 + g*8;
      int e1 = (16 + c)*512 + kt*32 + g*8;
      bf16x8 a0 = lds_bf8(ht + (e0 ^ ((c & 7) << 3)));
      bf16x8 a1 = lds_bf8(ht + (e1 ^ (((16 + c) & 7) << 3)));
      int kg = half*512 + kt*32 + g*8;
      bf16x8 b0 = ld_bf8(W2 + (size_t)(n0 +      c) * 1024 + kg);
      bf16x8 b1v= ld_bf8(W2 + (size_t)(n0 + 16 + c) * 1024 + kg);
      acc3[0][0] = MFMA(a0, b0, acc3[0][0]);
      acc3[0][1] = MFMA(a0, b1v, acc3[0][1]);
      acc3[1][0] = MFMA(a1, b0, acc3[1][0]);
      acc3[1][1] = MFMA(a1, b1v, acc3[1][1]);
    }
    __syncthreads();  // before ht overwrite
  }

  // ---- LN2 epilogue ----
  float val3[2][2][4];
  #pragma unroll
  for (int qt = 0; qt < 2; ++qt)
  #pragma unroll
  for (int nt = 0; nt < 2; ++nt)
  #pragma unroll
  for (int r = 0; r < 4; ++r){
    int col = n0 + nt*16 + c;
    val3[qt][nt][r] = acc3[qt][nt][r] + b2[col] + yv[qt][nt][r];
  }

  #pragma unroll
  for (int qt = 0; qt < 2; ++qt)
  #pragma unroll
  for (int r = 0; r < 4; ++r){
    float v0 = val3[qt][0][r], v1 = val3[qt][1][r];
    float p1 = rsum16(v0 + v1);
    float p2 = rsum16(v0*v0 + v1*v1);
    if (c == 0){
      int rr = qt*16 + g*4 + r;
      sm1[rr][w] = p1; sm2[rr][w] = p2;
    }
  }
  __syncthreads();

  #pragma unroll
  for (int qt = 0; qt < 2; ++qt)
  #pragma unroll
  for (int r = 0; r < 4; ++r){
    int rr = qt*16 + g*4 + r;
    float S1 = 0.f, S2 = 0.f;
    #pragma unroll
    for (int j = 0; j < 8; ++j){ S1 += sm1[rr][j]; S2 += sm2[rr][j]; }
    float mean = S1 * (1.0f/256.0f);
    float var  = S2 * (1.0f/256.0f) - mean*mean;
    float rstd = rsqrtf(var + 1e-5f);
    int mrow = m0 + rr;
    #pragma unroll
    for (int nt = 0; nt < 2; ++nt){
      int col = n0 + nt*16 + c;
      out[(size_t)mrow*256 + col] = (val3[qt][nt][r] - mean) * rstd * g2[col] + be2[col];
    }
  }
}

// ---------------- launcher ----------------------------------------------------
extern "C" void kernel_launch(void* const* d_in, const int* in_sizes, int n_in,
                              void* d_out, int out_size, void* d_ws, size_t ws_size,
                              hipStream_t stream)
{
  (void)in_sizes; (void)n_in; (void)out_size; (void)ws_size;
  const float* x   = (const float*)d_in[0];
  const float* pos = (const float*)d_in[1];
  const float* pad = (const float*)d_in[2];
  const float* Wq  = (const float*)d_in[3];
  const float* bq  = (const float*)d_in[4];
  const float* Wk  = (const float*)d_in[5];
  const float* bk  = (const float*)d_in[6];
  const float* Wv  = (const float*)d_in[7];
  const float* bv  = (const float*)d_in[8];
  const float* Wo  = (const float*)d_in[9];
  const float* bo  = (const float*)d_in[10];
  const float* W1  = (const float*)d_in[11];
  const float* b1  = (const float*)d_in[12];
  const float* W2  = (const float*)d_in[13];
  const float* b2  = (const float*)d_in[14];
  const float* g1  = (const float*)d_in[15];
  const float* be1 = (const float*)d_in[16];
  const float* g2  = (const float*)d_in[17];
  const float* be2 = (const float*)d_in[18];

  char* ws = (char*)d_ws;
  u16* wsX  = (u16*)(ws + OFF_X);
  u16* wsW3 = (u16*)(ws + OFF_WQ);
  u16* wsWo = (u16*)(ws + OFF_WO);
  u16* wsW1 = (u16*)(ws + OFF_W1);
  u16* wsW2 = (u16*)(ws + OFF_W2);
  u16* Qb   = (u16*)(ws + OFF_Q);
  u16* Kb   = (u16*)(ws + OFF_K);
  u16* VTb  = (u16*)(ws + OFF_VT);
  u16* ctx  = (u16*)(ws + OFF_CTX);

  prep_kernel<<<2816, 256, 0, stream>>>(x, Wq, Wk, Wv, Wo, W1, W2, wsX);
  qkv_kernel<<<dim3(256, 3), 512, 0, stream>>>(wsX, wsW3, bq, bk, bv, Qb, Kb, VTb);
  attn_kernel<<<512, 512, 0, stream>>>(pos, pad, Qb, Kb, VTb, ctx);
  tail_kernel<<<256, 512, 0, stream>>>(ctx, wsWo, bo, x, g1, be1,
                                       wsW1, b1, wsW2, b2, g2, be2, (float*)d_out);
}

// Round 9
// 228.387 us; speedup vs baseline: 1.2300x; 1.2300x over previous
//
#include <hip/hip_runtime.h>

typedef unsigned short u16;
typedef unsigned int   u32;
typedef float f32x4 __attribute__((ext_vector_type(4)));
typedef u32   u32x4 __attribute__((ext_vector_type(4)));
typedef u16   u16x4 __attribute__((ext_vector_type(4)));
typedef u16   u16x8 __attribute__((ext_vector_type(8)));
typedef __bf16 bf16x8 __attribute__((ext_vector_type(8)));

// ---------------- workspace byte offsets ----------
#define OFF_X    0x0000000ULL
#define OFF_WQ   0x0400000ULL
#define OFF_WO   0x0460000ULL
#define OFF_W1   0x0480000ULL
#define OFF_W2   0x0500000ULL
#define OFF_Q    0x0580000ULL
#define OFF_K    0x0980000ULL
#define OFF_VT   0x0D80000ULL
#define OFF_CTX  0x1180000ULL

__device__ __forceinline__ u16 f2bf(float f){
  u32 u = __float_as_uint(f);
  return (u16)((u + 0x7FFFu + ((u >> 16) & 1u)) >> 16);
}
__device__ __forceinline__ u32 cvt_pk(float lo, float hi){
  u32 r;
  asm volatile("v_cvt_pk_bf16_f32 %0, %1, %2" : "=v"(r) : "v"(lo), "v"(hi));
  return r;
}
__device__ __forceinline__ bf16x8 ld_bf8(const u16* p){
  return *(const bf16x8*)p;
}
__device__ __forceinline__ bf16x8 lds_bf8(const u16* p){
  return *(const bf16x8*)p;
}
__device__ __forceinline__ f32x4 ntld4(const float* p){
  return __builtin_nontemporal_load((const f32x4*)p);
}
__device__ __forceinline__ float ntld(const float* p){
  return __builtin_nontemporal_load(p);
}
__device__ __forceinline__ f32x4 MFMA(bf16x8 a, bf16x8 b, f32x4 c){
  return __builtin_amdgcn_mfma_f32_16x16x32_bf16(a, b, c, 0, 0, 0);
}
// barrier WITHOUT the vmcnt(0) drain: only LDS writes must be visible.
__device__ __forceinline__ void lbar(){
  asm volatile("s_waitcnt lgkmcnt(0)" ::: "memory");
  __builtin_amdgcn_s_barrier();
}
template<int C>
__device__ __forceinline__ float dpp_rot(float x){
  int i = __float_as_int(x);
  return __int_as_float(__builtin_amdgcn_update_dpp(i, i, C, 0xF, 0xF, false));
}
__device__ __forceinline__ float rmax16(float x){
  x = fmaxf(x, dpp_rot<0x121>(x)); x = fmaxf(x, dpp_rot<0x122>(x));
  x = fmaxf(x, dpp_rot<0x124>(x)); x = fmaxf(x, dpp_rot<0x128>(x));
  return x;
}
__device__ __forceinline__ float rsum16(float x){
  x += dpp_rot<0x121>(x); x += dpp_rot<0x122>(x);
  x += dpp_rot<0x124>(x); x += dpp_rot<0x128>(x);
  return x;
}

// ---------------- kernel 0: convert x + all weights to bf16 (x4 vectorized) ---
__global__ __launch_bounds__(256) void prep_kernel(
    const float* __restrict__ x,  const float* __restrict__ Wq,
    const float* __restrict__ Wk, const float* __restrict__ Wv,
    const float* __restrict__ Wo, const float* __restrict__ W1,
    const float* __restrict__ W2, u16* __restrict__ dst)
{
  int i = (blockIdx.x * 256 + threadIdx.x) * 4;   // grid 2816 -> exactly 2883584
  const float* src;
  int off;
  if (i < 2097152){ src = x; off = i; }
  else {
    int j = i - 2097152;
    if      (j <  65536){ src = Wq; off = j; }
    else if (j < 131072){ src = Wk; off = j -  65536; }
    else if (j < 196608){ src = Wv; off = j - 131072; }
    else if (j < 262144){ src = Wo; off = j - 196608; }
    else if (j < 524288){ src = W1; off = j - 262144; }
    else                { src = W2; off = j - 524288; }
  }
  f32x4 v = *(const f32x4*)(src + off);
  u16x4 o;
  o[0] = f2bf(v[0]); o[1] = f2bf(v[1]); o[2] = f2bf(v[2]); o[3] = f2bf(v[3]);
  *(u16x4*)(dst + i) = o;
}

// ---------------- kernel 1: QKV projection ------------------------------------
__global__ __launch_bounds__(512) void qkv_kernel(
    const u16* __restrict__ X, const u16* __restrict__ W3,
    const float* __restrict__ bq, const float* __restrict__ bk,
    const float* __restrict__ bv,
    u16* __restrict__ Q, u16* __restrict__ K, u16* __restrict__ VT)
{
  __shared__ u16 vtile[32][264];
  const int tid = threadIdx.x;
  const int lane = tid & 63, w = tid >> 6;
  const int g = lane >> 4, c = lane & 15;
  const int m0 = blockIdx.x * 32;
  const int nb = blockIdx.y;
  const u16* Wb = W3 + nb * 65536;
  const float* bias = (nb == 0) ? bq : ((nb == 1) ? bk : bv);
  const int n0 = w * 32;

  f32x4 acc[2][2];
  #pragma unroll
  for (int i = 0; i < 2; ++i)
    #pragma unroll
    for (int j = 0; j < 2; ++j){ f32x4 z = {0.f,0.f,0.f,0.f}; acc[i][j] = z; }

  #pragma unroll
  for (int kt = 0; kt < 8; ++kt){
    bf16x8 a0 = ld_bf8(X  + (size_t)(m0 +      c) * 256 + kt*32 + g*8);
    bf16x8 a1 = ld_bf8(X  + (size_t)(m0 + 16 + c) * 256 + kt*32 + g*8);
    bf16x8 b0 = ld_bf8(Wb + (size_t)(n0 +      c) * 256 + kt*32 + g*8);
    bf16x8 b1 = ld_bf8(Wb + (size_t)(n0 + 16 + c) * 256 + kt*32 + g*8);
    acc[0][0] = MFMA(a0, b0, acc[0][0]);
    acc[0][1] = MFMA(a0, b1, acc[0][1]);
    acc[1][0] = MFMA(a1, b0, acc[1][0]);
    acc[1][1] = MFMA(a1, b1, acc[1][1]);
  }

  const int bi = m0 >> 11, tbase = m0 & 2047;

  if (nb == 2){
    #pragma unroll
    for (int qt = 0; qt < 2; ++qt)
    #pragma unroll
    for (int nt = 0; nt < 2; ++nt)
    #pragma unroll
    for (int r = 0; r < 4; ++r){
      int row = qt*16 + g*4 + r;
      int col = n0 + nt*16 + c;
      vtile[row][col] = f2bf(acc[qt][nt][r] + bias[col]);
    }
    __syncthreads();
    #pragma unroll
    for (int s = 0; s < 2; ++s){
      int u = tid*2 + s;              // 0..1023
      int h = u >> 7, d = (u >> 2) & 31, sl0 = (u & 3) * 8;
      u16x8 o;
      #pragma unroll
      for (int jj = 0; jj < 8; ++jj){
        int sl = sl0 + jj;
        int tt = (sl >> 1) + ((sl & 1) << 4);   // stored slot sl holds t-offset
        o[jj] = vtile[tt][h*32 + d];
      }
      *(u16x8*)(VT + ((size_t)(bi*8 + h) * 32 + d) * 2048 + tbase + sl0) = o;
    }
  } else {
    #pragma unroll
    for (int qt = 0; qt < 2; ++qt)
    #pragma unroll
    for (int nt = 0; nt < 2; ++nt)
    #pragma unroll
    for (int r = 0; r < 4; ++r){
      int mrow = m0 + qt*16 + g*4 + r;
      int col  = n0 + nt*16 + c;
      float v = acc[qt][nt][r] + bias[col];
      int t = mrow & 2047;
      int h = col >> 5, d = col & 31;
      u16 hv = f2bf(v);
      if (nb == 0) Q[((size_t)(bi*8 + h) * 2048 + t) * 32 + d] = hv;
      else         K[((size_t)(bi*8 + h) * 2048 + t) * 32 + d] = hv;
    }
  }
}

// ---------------- kernel 2: fused flash attention with pos bias ---------------
// R6/R7 structure (512 WGs XCD-swizzled, 16 q-rows, 8 waves = 8 heads, 64-k
// tiles, packed bf16 bias double-buffered, K(t+1) reg prefetch, lgkm-only
// barrier). NEW vs R7:
//  (1) k-start STAGGER: WG starts at tile (bid>>3)&31 and wraps — online
//      softmax is k-order invariant; co-resident WGs get a 1-tile phase offset
//      so one WG's memory phase overlaps the other's VALU/LDS phase.
//  (2) s_setprio(1) around the QK/softmax/PV compute region (T5) — pays when
//      co-resident waves are at different phases.
__global__ __launch_bounds__(512, 4) void attn_kernel(
    const float* __restrict__ pos, const float* __restrict__ pad,
    const u16* __restrict__ Q, const u16* __restrict__ K,
    const u16* __restrict__ VT, u16* __restrict__ ctx)
{
  __shared__ u32 bias_lds[2][4608];   // [buf][h*576 + qr*36 + col]
  __shared__ u32 p_lds[8][16][34];

  const int tid = threadIdx.x;
  const int lane = tid & 63, w = tid >> 6;
  const int g = lane >> 4, c = lane & 15;
  const int bid = blockIdx.x;
  const int xcd = bid & 7;
  const int b = xcd >> 1;
  const int qtile = ((bid >> 3) << 1) | (xcd & 1);
  const int q0 = qtile * 16;
  const int start = (bid >> 3) & 31;   // k-loop phase stagger

  const u16* Qb  = Q  + ((size_t)(b*8 + w) * 2048 + q0) * 32;
  const u16* Kb  = K  +  (size_t)(b*8 + w) * 2048 * 32;
  const u16* VTb = VT +  (size_t)(b*8 + w) * 32 * 2048;

  const float c1 = 1.4426950408889634f * 0.17677669529663689f; // log2e / sqrt(32)
  const float c2 = 1.4426950408889634f;                        // log2e

  bf16x8 qf = ld_bf8(Qb + (size_t)c * 32 + g*8);

  f32x4 O[2];
  { f32x4 z = {0.f,0.f,0.f,0.f}; O[0] = z; O[1] = z; }
  float m_[4], l_[4];
  #pragma unroll
  for (int r = 0; r < 4; ++r){ m_[r] = -3.0e38f; l_[r] = 0.f; }

  const int li = (lane >> 1) & 15;
  const int ls = lane >> 5;
  const int h0 = (lane & 1) * 4;

  f32x4 fa[2], fb[2];
  float pa_[2], pb_[2];
  bf16x8 kf[4], knf[4], vf[4];

  auto stage_load = [&](int k0){
    #pragma unroll
    for (int j = 0; j < 2; ++j){
      int qr = w*2 + j;
      int k1 = ls*32 + li;
      const float* pr = pos + ((size_t)(b*2048 + q0 + qr) * 2048 + k0) * 8 + h0;
      fa[j] = ntld4(pr + (size_t)k1 * 8);
      fb[j] = ntld4(pr + (size_t)(k1 + 16) * 8);
      const float* dr = pad + (size_t)(b*2048 + q0 + qr) * 2048 + k0 + k1;
      pa_[j] = ntld(dr);
      pb_[j] = ntld(dr + 16);
    }
  };
  auto stage_write = [&](u32* bl){
    #pragma unroll
    for (int j = 0; j < 2; ++j){
      int qr = w*2 + j;
      float plo = pa_[j] * c2, phi = pb_[j] * c2;
      int base = qr*36 + ls*16 + li;
      #pragma unroll
      for (int j2 = 0; j2 < 4; ++j2){
        float lo = fmaf(fa[j][j2], c1, plo);
        float hi = fmaf(fb[j][j2], c1, phi);
        bl[(h0 + j2)*576 + base] = cvt_pk(lo, hi);
      }
    }
  };
  auto load_k = [&](int k0, bf16x8* kd){
    kd[0] = ld_bf8(Kb + (size_t)(k0 +      c) * 32 + g*8);
    kd[1] = ld_bf8(Kb + (size_t)(k0 + 16 + c) * 32 + g*8);
    kd[2] = ld_bf8(Kb + (size_t)(k0 + 32 + c) * 32 + g*8);
    kd[3] = ld_bf8(Kb + (size_t)(k0 + 48 + c) * 32 + g*8);
  };
  auto load_v = [&](int k0){
    vf[0] = ld_bf8(VTb + (size_t)(     c) * 2048 + k0      + g*8);
    vf[1] = ld_bf8(VTb + (size_t)(16 + c) * 2048 + k0      + g*8);
    vf[2] = ld_bf8(VTb + (size_t)(     c) * 2048 + k0 + 32 + g*8);
    vf[3] = ld_bf8(VTb + (size_t)(16 + c) * 2048 + k0 + 32 + g*8);
  };

  // prologue: tile `start` bias -> buf0; tile start+1 pos in regs; K(start) in regs
  stage_load(start * 64);
  stage_write(&bias_lds[0][0]);
  stage_load(((start + 1) & 31) * 64);
  load_k(start * 64, kf);
  lbar();

  for (int i = 0; i < 32; ++i){
    const int k0 = ((start + i) & 31) * 64;
    // 1. V for this tile (consumed late, by PV)
    load_v(k0);
    // 2. commit bias(i+1) from regs (loads issued at i-1)
    if (i < 31) stage_write(&bias_lds[(i + 1) & 1][0]);
    // 3. refill staging regs with pos/pad for tile i+2
    if (i < 30) stage_load(((start + i + 2) & 31) * 64);
    // 4. prefetch K for tile i+1
    if (i < 31) load_k(((start + i + 1) & 31) * 64, knf);

    __builtin_amdgcn_s_setprio(1);

    // 5. QK^T for all 64 k
    f32x4 sS[4];
    {
      f32x4 z = {0.f,0.f,0.f,0.f};
      sS[0] = MFMA(qf, kf[0], z);
      sS[1] = MFMA(qf, kf[1], z);
      sS[2] = MFMA(qf, kf[2], z);
      sS[3] = MFMA(qf, kf[3], z);
    }

    // 6. merged softmax over 64 k per row
    const u32* blc = &bias_lds[i & 1][w*576];
    #pragma unroll
    for (int r = 0; r < 4; ++r){
      int rowb = (g*4 + r)*36;
      u32 dwA = blc[rowb + c];
      u32 dwB = blc[rowb + 16 + c];
      float v0 = fmaf(sS[0][r], c1, __uint_as_float(dwA << 16));
      float v1 = fmaf(sS[1][r], c1, __uint_as_float(dwA & 0xFFFF0000u));
      float v2 = fmaf(sS[2][r], c1, __uint_as_float(dwB << 16));
      float v3 = fmaf(sS[3][r], c1, __uint_as_float(dwB & 0xFFFF0000u));
      float mx = rmax16(fmaxf(fmaxf(v0, v1), fmaxf(v2, v3)));
      float mo = m_[r];
      float mn = fmaxf(mo, mx);
      float alpha = exp2f(mo - mn);
      m_[r] = mn;
      float p0 = exp2f(v0 - mn);
      float p1 = exp2f(v1 - mn);
      float p2 = exp2f(v2 - mn);
      float p3 = exp2f(v3 - mn);
      float ps = rsum16((p0 + p1) + (p2 + p3));
      l_[r] = l_[r] * alpha + ps;
      O[0][r] *= alpha;
      O[1][r] *= alpha;
      p_lds[w][g*4 + r][c]      = cvt_pk(p0, p1);
      p_lds[w][g*4 + r][16 + c] = cvt_pk(p2, p3);
    }

    // 7. PV: P as A-fragments (per-wave LDS transpose), V as B
    {
      u32x4 t0 = { p_lds[w][c][g*4 + 0], p_lds[w][c][g*4 + 1],
                   p_lds[w][c][g*4 + 2], p_lds[w][c][g*4 + 3] };
      u32x4 t1 = { p_lds[w][c][16 + g*4 + 0], p_lds[w][c][16 + g*4 + 1],
                   p_lds[w][c][16 + g*4 + 2], p_lds[w][c][16 + g*4 + 3] };
      bf16x8 pa0 = __builtin_bit_cast(bf16x8, t0);
      bf16x8 pa1 = __builtin_bit_cast(bf16x8, t1);
      O[0] = MFMA(pa0, vf[0], O[0]);
      O[1] = MFMA(pa0, vf[1], O[1]);
      O[0] = MFMA(pa1, vf[2], O[0]);
      O[1] = MFMA(pa1, vf[3], O[1]);
    }

    __builtin_amdgcn_s_setprio(0);

    // 8. rotate K regs, barrier (lgkm only; global loads stay in flight)
    #pragma unroll
    for (int j = 0; j < 4; ++j) kf[j] = knf[j];
    lbar();
  }

  // epilogue: normalize and store ctx (B*T, 256) bf16
  #pragma unroll
  for (int r = 0; r < 4; ++r){
    float inv = 1.0f / l_[r];
    int q = q0 + g*4 + r;
    size_t base = (size_t)(b*2048 + q) * 256 + w*32;
    ctx[base +      c] = f2bf(O[0][r] * inv);
    ctx[base + 16 + c] = f2bf(O[1][r] * inv);
  }
}

// ---------------- kernel 3: fused tail: Wo+LN1 -> FFN1+LeakyReLU -> FFN2+LN2 --
__global__ __launch_bounds__(512, 2) void tail_kernel(
    const u16* __restrict__ ctx, const u16* __restrict__ Wo,
    const float* __restrict__ bo, const float* __restrict__ x,
    const float* __restrict__ g1, const float* __restrict__ be1,
    const u16* __restrict__ W1, const float* __restrict__ b1,
    const u16* __restrict__ W2, const float* __restrict__ b2,
    const float* __restrict__ g2, const float* __restrict__ be2,
    float* __restrict__ out)
{
  __shared__ u16 x1t[32*256];     // 16 KB
  __shared__ u16 ht[32*512];      // 32 KB (one 512-col half of h)
  __shared__ float sm1[32][8], sm2[32][8];

  const int tid = threadIdx.x;
  const int lane = tid & 63, w = tid >> 6;
  const int g = lane >> 4, c = lane & 15;
  const int m0 = blockIdx.x * 32;
  const int n0 = w * 32;

  // ---- phase A: Wo GEMM (K=256) + bias + residual + LN1 ----
  f32x4 acc[2][2];
  #pragma unroll
  for (int i = 0; i < 2; ++i)
    #pragma unroll
    for (int j = 0; j < 2; ++j){ f32x4 z = {0.f,0.f,0.f,0.f}; acc[i][j] = z; }

  #pragma unroll
  for (int kt = 0; kt < 8; ++kt){
    bf16x8 a0 = ld_bf8(ctx + (size_t)(m0 +      c) * 256 + kt*32 + g*8);
    bf16x8 a1 = ld_bf8(ctx + (size_t)(m0 + 16 + c) * 256 + kt*32 + g*8);
    bf16x8 b0 = ld_bf8(Wo  + (size_t)(n0 +      c) * 256 + kt*32 + g*8);
    bf16x8 b1v= ld_bf8(Wo  + (size_t)(n0 + 16 + c) * 256 + kt*32 + g*8);
    acc[0][0] = MFMA(a0, b0, acc[0][0]);
    acc[0][1] = MFMA(a0, b1v, acc[0][1]);
    acc[1][0] = MFMA(a1, b0, acc[1][0]);
    acc[1][1] = MFMA(a1, b1v, acc[1][1]);
  }

  float val[2][2][4];
  #pragma unroll
  for (int qt = 0; qt < 2; ++qt)
  #pragma unroll
  for (int nt = 0; nt < 2; ++nt)
  #pragma unroll
  for (int r = 0; r < 4; ++r){
    int mrow = m0 + qt*16 + g*4 + r;
    int col  = n0 + nt*16 + c;
    val[qt][nt][r] = acc[qt][nt][r] + bo[col] + x[(size_t)mrow*256 + col];
  }

  #pragma unroll
  for (int qt = 0; qt < 2; ++qt)
  #pragma unroll
  for (int r = 0; r < 4; ++r){
    float v0 = val[qt][0][r], v1 = val[qt][1][r];
    float p1 = rsum16(v0 + v1);
    float p2 = rsum16(v0*v0 + v1*v1);
    if (c == 0){
      int rr = qt*16 + g*4 + r;
      sm1[rr][w] = p1; sm2[rr][w] = p2;
    }
  }
  __syncthreads();  // #1

  float yv[2][2][4];   // LN1 output, kept as LN2 residual
  #pragma unroll
  for (int qt = 0; qt < 2; ++qt)
  #pragma unroll
  for (int r = 0; r < 4; ++r){
    int rr = qt*16 + g*4 + r;
    float S1 = 0.f, S2 = 0.f;
    #pragma unroll
    for (int j = 0; j < 8; ++j){ S1 += sm1[rr][j]; S2 += sm2[rr][j]; }
    float mean = S1 * (1.0f/256.0f);
    float var  = S2 * (1.0f/256.0f) - mean*mean;
    float rstd = rsqrtf(var + 1e-5f);
    #pragma unroll
    for (int nt = 0; nt < 2; ++nt){
      int col = n0 + nt*16 + c;
      float y = (val[qt][nt][r] - mean) * rstd * g1[col] + be1[col];
      yv[qt][nt][r] = y;
      int elem = rr*256 + col;
      x1t[elem ^ ((rr & 7) << 3)] = f2bf(y);
    }
  }
  __syncthreads();  // #2: x1t visible

  f32x4 acc3[2][2];
  #pragma unroll
  for (int i = 0; i < 2; ++i)
    #pragma unroll
    for (int j = 0; j < 2; ++j){ f32x4 z = {0.f,0.f,0.f,0.f}; acc3[i][j] = z; }

  #pragma unroll
  for (int half = 0; half < 2; ++half){
    // ---- phase B: FFN1 for cols [half*512, half*512+512) + LeakyReLU -> ht ----
    #pragma unroll
    for (int ns = 0; ns < 2; ++ns){
      const int ncol = half*512 + w*64 + ns*32;   // global h col base
      f32x4 acc2[2][2];
      #pragma unroll
      for (int i = 0; i < 2; ++i)
        #pragma unroll
        for (int j = 0; j < 2; ++j){ f32x4 z = {0.f,0.f,0.f,0.f}; acc2[i][j] = z; }
      #pragma unroll
      for (int kt = 0; kt < 8; ++kt){
        int e0 = (     c)*256 + kt*32 + g*8;
        int e1 = (16 + c)*256 + kt*32 + g*8;
        bf16x8 a0 = lds_bf8(x1t + (e0 ^ ((c & 7) << 3)));
        bf16x8 a1 = lds_bf8(x1t + (e1 ^ (((16 + c) & 7) << 3)));
        bf16x8 b0 = ld_bf8(W1 + (size_t)(ncol +      c) * 256 + kt*32 + g*8);
        bf16x8 b1v= ld_bf8(W1 + (size_t)(ncol + 16 + c) * 256 + kt*32 + g*8);
        acc2[0][0] = MFMA(a0, b0, acc2[0][0]);
        acc2[0][1] = MFMA(a0, b1v, acc2[0][1]);
        acc2[1][0] = MFMA(a1, b0, acc2[1][0]);
        acc2[1][1] = MFMA(a1, b1v, acc2[1][1]);
      }
      #pragma unroll
      for (int qt = 0; qt < 2; ++qt)
      #pragma unroll
      for (int nt = 0; nt < 2; ++nt)
      #pragma unroll
      for (int r = 0; r < 4; ++r){
        int row = qt*16 + g*4 + r;
        int gcol = ncol + nt*16 + c;
        float v = acc2[qt][nt][r] + b1[gcol];
        v = (v >= 0.f) ? v : v * 0.01f;
        int elem = row*512 + (gcol - half*512);
        ht[elem ^ ((row & 7) << 3)] = f2bf(v);
      }
    }
    __syncthreads();  // ht ready

    // ---- phase C: FFN2 partial K (512 cols of this half) ----
    #pragma unroll
    for (int kt = 0; kt < 16; ++kt){
      int e0 = (     c)*512 + kt*32 + g*8;
      int e1 = (16 + c)*512 + kt*32 + g*8;
      bf16x8 a0 = lds_bf8(ht + (e0 ^ ((c & 7) << 3)));
      bf16x8 a1 = lds_bf8(ht + (e1 ^ (((16 + c) & 7) << 3)));
      int kg = half*512 + kt*32 + g*8;
      bf16x8 b0 = ld_bf8(W2 + (size_t)(n0 +      c) * 1024 + kg);
      bf16x8 b1v= ld_bf8(W2 + (size_t)(n0 + 16 + c) * 1024 + kg);
      acc3[0][0] = MFMA(a0, b0, acc3[0][0]);
      acc3[0][1] = MFMA(a0, b1v, acc3[0][1]);
      acc3[1][0] = MFMA(a1, b0, acc3[1][0]);
      acc3[1][1] = MFMA(a1, b1v, acc3[1][1]);
    }
    __syncthreads();  // before ht overwrite
  }

  // ---- LN2 epilogue ----
  float val3[2][2][4];
  #pragma unroll
  for (int qt = 0; qt < 2; ++qt)
  #pragma unroll
  for (int nt = 0; nt < 2; ++nt)
  #pragma unroll
  for (int r = 0; r < 4; ++r){
    int col = n0 + nt*16 + c;
    val3[qt][nt][r] = acc3[qt][nt][r] + b2[col] + yv[qt][nt][r];
  }

  #pragma unroll
  for (int qt = 0; qt < 2; ++qt)
  #pragma unroll
  for (int r = 0; r < 4; ++r){
    float v0 = val3[qt][0][r], v1 = val3[qt][1][r];
    float p1 = rsum16(v0 + v1);
    float p2 = rsum16(v0*v0 + v1*v1);
    if (c == 0){
      int rr = qt*16 + g*4 + r;
      sm1[rr][w] = p1; sm2[rr][w] = p2;
    }
  }
  __syncthreads();

  #pragma unroll
  for (int qt = 0; qt < 2; ++qt)
  #pragma unroll
  for (int r = 0; r < 4; ++r){
    int rr = qt*16 + g*4 + r;
    float S1 = 0.f, S2 = 0.f;
    #pragma unroll
    for (int j = 0; j < 8; ++j){ S1 += sm1[rr][j]; S2 += sm2[rr][j]; }
    float mean = S1 * (1.0f/256.0f);
    float var  = S2 * (1.0f/256.0f) - mean*mean;
    float rstd = rsqrtf(var + 1e-5f);
    int mrow = m0 + rr;
    #pragma unroll
    for (int nt = 0; nt < 2; ++nt){
      int col = n0 + nt*16 + c;
      out[(size_t)mrow*256 + col] = (val3[qt][nt][r] - mean) * rstd * g2[col] + be2[col];
    }
  }
}

// ---------------- launcher ----------------------------------------------------
extern "C" void kernel_launch(void* const* d_in, const int* in_sizes, int n_in,
                              void* d_out, int out_size, void* d_ws, size_t ws_size,
                              hipStream_t stream)
{
  (void)in_sizes; (void)n_in; (void)out_size; (void)ws_size;
  const float* x   = (const float*)d_in[0];
  const float* pos = (const float*)d_in[1];
  const float* pad = (const float*)d_in[2];
  const float* Wq  = (const float*)d_in[3];
  const float* bq  = (const float*)d_in[4];
  const float* Wk  = (const float*)d_in[5];
  const float* bk  = (const float*)d_in[6];
  const float* Wv  = (const float*)d_in[7];
  const float* bv  = (const float*)d_in[8];
  const float* Wo  = (const float*)d_in[9];
  const float* bo  = (const float*)d_in[10];
  const float* W1  = (const float*)d_in[11];
  const float* b1  = (const float*)d_in[12];
  const float* W2  = (const float*)d_in[13];
  const float* b2  = (const float*)d_in[14];
  const float* g1  = (const float*)d_in[15];
  const float* be1 = (const float*)d_in[16];
  const float* g2  = (const float*)d_in[17];
  const float* be2 = (const float*)d_in[18];

  char* ws = (char*)d_ws;
  u16* wsX  = (u16*)(ws + OFF_X);
  u16* wsW3 = (u16*)(ws + OFF_WQ);
  u16* wsWo = (u16*)(ws + OFF_WO);
  u16* wsW1 = (u16*)(ws + OFF_W1);
  u16* wsW2 = (u16*)(ws + OFF_W2);
  u16* Qb   = (u16*)(ws + OFF_Q);
  u16* Kb   = (u16*)(ws + OFF_K);
  u16* VTb  = (u16*)(ws + OFF_VT);
  u16* ctx  = (u16*)(ws + OFF_CTX);

  prep_kernel<<<2816, 256, 0, stream>>>(x, Wq, Wk, Wv, Wo, W1, W2, wsX);
  qkv_kernel<<<dim3(256, 3), 512, 0, stream>>>(wsX, wsW3, bq, bk, bv, Qb, Kb, VTb);
  attn_kernel<<<512, 512, 0, stream>>>(pos, pad, Qb, Kb, VTb, ctx);
  tail_kernel<<<256, 512, 0, stream>>>(ctx, wsWo, bo, x, g1, be1,
                                       wsW1, b1, wsW2, b2, g2, be2, (float*)d_out);
}

// Round 10
// 227.963 us; speedup vs baseline: 1.2323x; 1.0019x over previous
//
#include <hip/hip_runtime.h>

typedef unsigned short u16;
typedef unsigned int   u32;
typedef float f32x4 __attribute__((ext_vector_type(4)));
typedef u32   u32x4 __attribute__((ext_vector_type(4)));
typedef u16   u16x4 __attribute__((ext_vector_type(4)));
typedef u16   u16x8 __attribute__((ext_vector_type(8)));
typedef __bf16 bf16x8 __attribute__((ext_vector_type(8)));

// ---------------- workspace byte offsets ----------
#define OFF_X    0x0000000ULL
#define OFF_WQ   0x0400000ULL
#define OFF_WO   0x0460000ULL
#define OFF_W1   0x0480000ULL
#define OFF_W2   0x0500000ULL
#define OFF_Q    0x0580000ULL
#define OFF_K    0x0980000ULL
#define OFF_VT   0x0D80000ULL
#define OFF_CTX  0x1180000ULL

__device__ __forceinline__ u16 f2bf(float f){
  u32 u = __float_as_uint(f);
  return (u16)((u + 0x7FFFu + ((u >> 16) & 1u)) >> 16);
}
__device__ __forceinline__ u32 cvt_pk(float lo, float hi){
  u32 r;
  asm volatile("v_cvt_pk_bf16_f32 %0, %1, %2" : "=v"(r) : "v"(lo), "v"(hi));
  return r;
}
__device__ __forceinline__ bf16x8 ld_bf8(const u16* p){
  return *(const bf16x8*)p;
}
__device__ __forceinline__ bf16x8 lds_bf8(const u16* p){
  return *(const bf16x8*)p;
}
__device__ __forceinline__ f32x4 ntld4(const float* p){
  return __builtin_nontemporal_load((const f32x4*)p);
}
__device__ __forceinline__ float ntld(const float* p){
  return __builtin_nontemporal_load(p);
}
__device__ __forceinline__ f32x4 MFMA(bf16x8 a, bf16x8 b, f32x4 c){
  return __builtin_amdgcn_mfma_f32_16x16x32_bf16(a, b, c, 0, 0, 0);
}
// barrier WITHOUT the vmcnt(0) drain: only LDS writes must be visible.
__device__ __forceinline__ void lbar(){
  asm volatile("s_waitcnt lgkmcnt(0)" ::: "memory");
  __builtin_amdgcn_s_barrier();
}
template<int C>
__device__ __forceinline__ float dpp_rot(float x){
  int i = __float_as_int(x);
  return __int_as_float(__builtin_amdgcn_update_dpp(i, i, C, 0xF, 0xF, false));
}
__device__ __forceinline__ float rmax16(float x){
  x = fmaxf(x, dpp_rot<0x121>(x)); x = fmaxf(x, dpp_rot<0x122>(x));
  x = fmaxf(x, dpp_rot<0x124>(x)); x = fmaxf(x, dpp_rot<0x128>(x));
  return x;
}
__device__ __forceinline__ float rsum16(float x){
  x += dpp_rot<0x121>(x); x += dpp_rot<0x122>(x);
  x += dpp_rot<0x124>(x); x += dpp_rot<0x128>(x);
  return x;
}

// ---------------- kernel 0: convert x + all weights to bf16 (x4 vectorized) ---
__global__ __launch_bounds__(256) void prep_kernel(
    const float* __restrict__ x,  const float* __restrict__ Wq,
    const float* __restrict__ Wk, const float* __restrict__ Wv,
    const float* __restrict__ Wo, const float* __restrict__ W1,
    const float* __restrict__ W2, u16* __restrict__ dst)
{
  int i = (blockIdx.x * 256 + threadIdx.x) * 4;   // grid 2816 -> exactly 2883584
  const float* src;
  int off;
  if (i < 2097152){ src = x; off = i; }
  else {
    int j = i - 2097152;
    if      (j <  65536){ src = Wq; off = j; }
    else if (j < 131072){ src = Wk; off = j -  65536; }
    else if (j < 196608){ src = Wv; off = j - 131072; }
    else if (j < 262144){ src = Wo; off = j - 196608; }
    else if (j < 524288){ src = W1; off = j - 262144; }
    else                { src = W2; off = j - 524288; }
  }
  f32x4 v = *(const f32x4*)(src + off);
  u16x4 o;
  o[0] = f2bf(v[0]); o[1] = f2bf(v[1]); o[2] = f2bf(v[2]); o[3] = f2bf(v[3]);
  *(u16x4*)(dst + i) = o;
}

// ---------------- kernel 1: QKV projection ------------------------------------
__global__ __launch_bounds__(512) void qkv_kernel(
    const u16* __restrict__ X, const u16* __restrict__ W3,
    const float* __restrict__ bq, const float* __restrict__ bk,
    const float* __restrict__ bv,
    u16* __restrict__ Q, u16* __restrict__ K, u16* __restrict__ VT)
{
  __shared__ u16 vtile[32][264];
  const int tid = threadIdx.x;
  const int lane = tid & 63, w = tid >> 6;
  const int g = lane >> 4, c = lane & 15;
  const int m0 = blockIdx.x * 32;
  const int nb = blockIdx.y;
  const u16* Wb = W3 + nb * 65536;
  const float* bias = (nb == 0) ? bq : ((nb == 1) ? bk : bv);
  const int n0 = w * 32;

  f32x4 acc[2][2];
  #pragma unroll
  for (int i = 0; i < 2; ++i)
    #pragma unroll
    for (int j = 0; j < 2; ++j){ f32x4 z = {0.f,0.f,0.f,0.f}; acc[i][j] = z; }

  #pragma unroll
  for (int kt = 0; kt < 8; ++kt){
    bf16x8 a0 = ld_bf8(X  + (size_t)(m0 +      c) * 256 + kt*32 + g*8);
    bf16x8 a1 = ld_bf8(X  + (size_t)(m0 + 16 + c) * 256 + kt*32 + g*8);
    bf16x8 b0 = ld_bf8(Wb + (size_t)(n0 +      c) * 256 + kt*32 + g*8);
    bf16x8 b1 = ld_bf8(Wb + (size_t)(n0 + 16 + c) * 256 + kt*32 + g*8);
    acc[0][0] = MFMA(a0, b0, acc[0][0]);
    acc[0][1] = MFMA(a0, b1, acc[0][1]);
    acc[1][0] = MFMA(a1, b0, acc[1][0]);
    acc[1][1] = MFMA(a1, b1, acc[1][1]);
  }

  const int bi = m0 >> 11, tbase = m0 & 2047;

  if (nb == 2){
    #pragma unroll
    for (int qt = 0; qt < 2; ++qt)
    #pragma unroll
    for (int nt = 0; nt < 2; ++nt)
    #pragma unroll
    for (int r = 0; r < 4; ++r){
      int row = qt*16 + g*4 + r;
      int col = n0 + nt*16 + c;
      vtile[row][col] = f2bf(acc[qt][nt][r] + bias[col]);
    }
    __syncthreads();
    #pragma unroll
    for (int s = 0; s < 2; ++s){
      int u = tid*2 + s;              // 0..1023
      int h = u >> 7, d = (u >> 2) & 31, sl0 = (u & 3) * 8;
      u16x8 o;
      #pragma unroll
      for (int jj = 0; jj < 8; ++jj){
        int sl = sl0 + jj;
        int tt = (sl >> 1) + ((sl & 1) << 4);   // stored slot sl holds t-offset
        o[jj] = vtile[tt][h*32 + d];
      }
      *(u16x8*)(VT + ((size_t)(bi*8 + h) * 32 + d) * 2048 + tbase + sl0) = o;
    }
  } else {
    #pragma unroll
    for (int qt = 0; qt < 2; ++qt)
    #pragma unroll
    for (int nt = 0; nt < 2; ++nt)
    #pragma unroll
    for (int r = 0; r < 4; ++r){
      int mrow = m0 + qt*16 + g*4 + r;
      int col  = n0 + nt*16 + c;
      float v = acc[qt][nt][r] + bias[col];
      int t = mrow & 2047;
      int h = col >> 5, d = col & 31;
      u16 hv = f2bf(v);
      if (nb == 0) Q[((size_t)(bi*8 + h) * 2048 + t) * 32 + d] = hv;
      else         K[((size_t)(bi*8 + h) * 2048 + t) * 32 + d] = hv;
    }
  }
}

// ---------------- kernel 2: fused flash attention with pos bias ---------------
// R6/R7 structure (512 WGs XCD-swizzled, 16 q-rows, 8 waves = 8 heads, 64-k
// tiles, packed bf16 bias double-buffered, K(t+1) reg prefetch, lgkm-only
// barrier). NEW vs R7:
//  (1) k-start STAGGER: WG starts at tile (bid>>3)&31 and wraps — online
//      softmax is k-order invariant; co-resident WGs get a 1-tile phase offset
//      so one WG's memory phase overlaps the other's VALU/LDS phase.
//  (2) s_setprio(1) around the QK/softmax/PV compute region (T5) — pays when
//      co-resident waves are at different phases.
__global__ __launch_bounds__(512, 4) void attn_kernel(
    const float* __restrict__ pos, const float* __restrict__ pad,
    const u16* __restrict__ Q, const u16* __restrict__ K,
    const u16* __restrict__ VT, u16* __restrict__ ctx)
{
  __shared__ u32 bias_lds[2][4608];   // [buf][h*576 + qr*36 + col]
  __shared__ u32 p_lds[8][16][34];

  const int tid = threadIdx.x;
  const int lane = tid & 63, w = tid >> 6;
  const int g = lane >> 4, c = lane & 15;
  const int bid = blockIdx.x;
  const int xcd = bid & 7;
  const int b = xcd >> 1;
  const int qtile = ((bid >> 3) << 1) | (xcd & 1);
  const int q0 = qtile * 16;
  const int start = (bid >> 3) & 31;   // k-loop phase stagger

  const u16* Qb  = Q  + ((size_t)(b*8 + w) * 2048 + q0) * 32;
  const u16* Kb  = K  +  (size_t)(b*8 + w) * 2048 * 32;
  const u16* VTb = VT +  (size_t)(b*8 + w) * 32 * 2048;

  const float c1 = 1.4426950408889634f * 0.17677669529663689f; // log2e / sqrt(32)
  const float c2 = 1.4426950408889634f;                        // log2e

  bf16x8 qf = ld_bf8(Qb + (size_t)c * 32 + g*8);

  f32x4 O[2];
  { f32x4 z = {0.f,0.f,0.f,0.f}; O[0] = z; O[1] = z; }
  float m_[4], l_[4];
  #pragma unroll
  for (int r = 0; r < 4; ++r){ m_[r] = -3.0e38f; l_[r] = 0.f; }

  const int li = (lane >> 1) & 15;
  const int ls = lane >> 5;
  const int h0 = (lane & 1) * 4;

  f32x4 fa[2], fb[2];
  float pa_[2], pb_[2];
  bf16x8 kf[4], knf[4], vf[4];

  auto stage_load = [&](int k0){
    #pragma unroll
    for (int j = 0; j < 2; ++j){
      int qr = w*2 + j;
      int k1 = ls*32 + li;
      const float* pr = pos + ((size_t)(b*2048 + q0 + qr) * 2048 + k0) * 8 + h0;
      fa[j] = ntld4(pr + (size_t)k1 * 8);
      fb[j] = ntld4(pr + (size_t)(k1 + 16) * 8);
      const float* dr = pad + (size_t)(b*2048 + q0 + qr) * 2048 + k0 + k1;
      pa_[j] = ntld(dr);
      pb_[j] = ntld(dr + 16);
    }
  };
  auto stage_write = [&](u32* bl){
    #pragma unroll
    for (int j = 0; j < 2; ++j){
      int qr = w*2 + j;
      float plo = pa_[j] * c2, phi = pb_[j] * c2;
      int base = qr*36 + ls*16 + li;
      #pragma unroll
      for (int j2 = 0; j2 < 4; ++j2){
        float lo = fmaf(fa[j][j2], c1, plo);
        float hi = fmaf(fb[j][j2], c1, phi);
        bl[(h0 + j2)*576 + base] = cvt_pk(lo, hi);
      }
    }
  };
  auto load_k = [&](int k0, bf16x8* kd){
    kd[0] = ld_bf8(Kb + (size_t)(k0 +      c) * 32 + g*8);
    kd[1] = ld_bf8(Kb + (size_t)(k0 + 16 + c) * 32 + g*8);
    kd[2] = ld_bf8(Kb + (size_t)(k0 + 32 + c) * 32 + g*8);
    kd[3] = ld_bf8(Kb + (size_t)(k0 + 48 + c) * 32 + g*8);
  };
  auto load_v = [&](int k0){
    vf[0] = ld_bf8(VTb + (size_t)(     c) * 2048 + k0      + g*8);
    vf[1] = ld_bf8(VTb + (size_t)(16 + c) * 2048 + k0      + g*8);
    vf[2] = ld_bf8(VTb + (size_t)(     c) * 2048 + k0 + 32 + g*8);
    vf[3] = ld_bf8(VTb + (size_t)(16 + c) * 2048 + k0 + 32 + g*8);
  };

  // prologue: tile `start` bias -> buf0; tile start+1 pos in regs; K(start) in regs
  stage_load(start * 64);
  stage_write(&bias_lds[0][0]);
  stage_load(((start + 1) & 31) * 64);
  load_k(start * 64, kf);
  lbar();

  for (int i = 0; i < 32; ++i){
    const int k0 = ((start + i) & 31) * 64;
    // 1. V for this tile (consumed late, by PV)
    load_v(k0);
    // 2. commit bias(i+1) from regs (loads issued at i-1)
    if (i < 31) stage_write(&bias_lds[(i + 1) & 1][0]);
    // 3. refill staging regs with pos/pad for tile i+2
    if (i < 30) stage_load(((start + i + 2) & 31) * 64);
    // 4. prefetch K for tile i+1
    if (i < 31) load_k(((start + i + 1) & 31) * 64, knf);

    __builtin_amdgcn_s_setprio(1);

    // 5. QK^T for all 64 k
    f32x4 sS[4];
    {
      f32x4 z = {0.f,0.f,0.f,0.f};
      sS[0] = MFMA(qf, kf[0], z);
      sS[1] = MFMA(qf, kf[1], z);
      sS[2] = MFMA(qf, kf[2], z);
      sS[3] = MFMA(qf, kf[3], z);
    }

    // 6. merged softmax over 64 k per row
    const u32* blc = &bias_lds[i & 1][w*576];
    #pragma unroll
    for (int r = 0; r < 4; ++r){
      int rowb = (g*4 + r)*36;
      u32 dwA = blc[rowb + c];
      u32 dwB = blc[rowb + 16 + c];
      float v0 = fmaf(sS[0][r], c1, __uint_as_float(dwA << 16));
      float v1 = fmaf(sS[1][r], c1, __uint_as_float(dwA & 0xFFFF0000u));
      float v2 = fmaf(sS[2][r], c1, __uint_as_float(dwB << 16));
      float v3 = fmaf(sS[3][r], c1, __uint_as_float(dwB & 0xFFFF0000u));
      float mx = rmax16(fmaxf(fmaxf(v0, v1), fmaxf(v2, v3)));
      float mo = m_[r];
      float mn = fmaxf(mo, mx);
      float alpha = exp2f(mo - mn);
      m_[r] = mn;
      float p0 = exp2f(v0 - mn);
      float p1 = exp2f(v1 - mn);
      float p2 = exp2f(v2 - mn);
      float p3 = exp2f(v3 - mn);
      float ps = rsum16((p0 + p1) + (p2 + p3));
      l_[r] = l_[r] * alpha + ps;
      O[0][r] *= alpha;
      O[1][r] *= alpha;
      p_lds[w][g*4 + r][c]      = cvt_pk(p0, p1);
      p_lds[w][g*4 + r][16 + c] = cvt_pk(p2, p3);
    }

    // 7. PV: P as A-fragments (per-wave LDS transpose), V as B
    {
      u32x4 t0 = { p_lds[w][c][g*4 + 0], p_lds[w][c][g*4 + 1],
                   p_lds[w][c][g*4 + 2], p_lds[w][c][g*4 + 3] };
      u32x4 t1 = { p_lds[w][c][16 + g*4 + 0], p_lds[w][c][16 + g*4 + 1],
                   p_lds[w][c][16 + g*4 + 2], p_lds[w][c][16 + g*4 + 3] };
      bf16x8 pa0 = __builtin_bit_cast(bf16x8, t0);
      bf16x8 pa1 = __builtin_bit_cast(bf16x8, t1);
      O[0] = MFMA(pa0, vf[0], O[0]);
      O[1] = MFMA(pa0, vf[1], O[1]);
      O[0] = MFMA(pa1, vf[2], O[0]);
      O[1] = MFMA(pa1, vf[3], O[1]);
    }

    __builtin_amdgcn_s_setprio(0);

    // 8. rotate K regs, barrier (lgkm only; global loads stay in flight)
    #pragma unroll
    for (int j = 0; j < 4; ++j) kf[j] = knf[j];
    lbar();
  }

  // epilogue: normalize and store ctx (B*T, 256) bf16
  #pragma unroll
  for (int r = 0; r < 4; ++r){
    float inv = 1.0f / l_[r];
    int q = q0 + g*4 + r;
    size_t base = (size_t)(b*2048 + q) * 256 + w*32;
    ctx[base +      c] = f2bf(O[0][r] * inv);
    ctx[base + 16 + c] = f2bf(O[1][r] * inv);
  }
}

// ---------------- kernel 3: fused tail: Wo+LN1 -> FFN1+LeakyReLU -> FFN2+LN2 --
__global__ __launch_bounds__(512, 2) void tail_kernel(
    const u16* __restrict__ ctx, const u16* __restrict__ Wo,
    const float* __restrict__ bo, const float* __restrict__ x,
    const float* __restrict__ g1, const float* __restrict__ be1,
    const u16* __restrict__ W1, const float* __restrict__ b1,
    const u16* __restrict__ W2, const float* __restrict__ b2,
    const float* __restrict__ g2, const float* __restrict__ be2,
    float* __restrict__ out)
{
  __shared__ u16 x1t[32*256];     // 16 KB
  __shared__ u16 ht[32*512];      // 32 KB (one 512-col half of h)
  __shared__ float sm1[32][8], sm2[32][8];

  const int tid = threadIdx.x;
  const int lane = tid & 63, w = tid >> 6;
  const int g = lane >> 4, c = lane & 15;
  const int m0 = blockIdx.x * 32;
  const int n0 = w * 32;

  // ---- phase A: Wo GEMM (K=256) + bias + residual + LN1 ----
  f32x4 acc[2][2];
  #pragma unroll
  for (int i = 0; i < 2; ++i)
    #pragma unroll
    for (int j = 0; j < 2; ++j){ f32x4 z = {0.f,0.f,0.f,0.f}; acc[i][j] = z; }

  #pragma unroll
  for (int kt = 0; kt < 8; ++kt){
    bf16x8 a0 = ld_bf8(ctx + (size_t)(m0 +      c) * 256 + kt*32 + g*8);
    bf16x8 a1 = ld_bf8(ctx + (size_t)(m0 + 16 + c) * 256 + kt*32 + g*8);
    bf16x8 b0 = ld_bf8(Wo  + (size_t)(n0 +      c) * 256 + kt*32 + g*8);
    bf16x8 b1v= ld_bf8(Wo  + (size_t)(n0 + 16 + c) * 256 + kt*32 + g*8);
    acc[0][0] = MFMA(a0, b0, acc[0][0]);
    acc[0][1] = MFMA(a0, b1v, acc[0][1]);
    acc[1][0] = MFMA(a1, b0, acc[1][0]);
    acc[1][1] = MFMA(a1, b1v, acc[1][1]);
  }

  float val[2][2][4];
  #pragma unroll
  for (int qt = 0; qt < 2; ++qt)
  #pragma unroll
  for (int nt = 0; nt < 2; ++nt)
  #pragma unroll
  for (int r = 0; r < 4; ++r){
    int mrow = m0 + qt*16 + g*4 + r;
    int col  = n0 + nt*16 + c;
    val[qt][nt][r] = acc[qt][nt][r] + bo[col] + x[(size_t)mrow*256 + col];
  }

  #pragma unroll
  for (int qt = 0; qt < 2; ++qt)
  #pragma unroll
  for (int r = 0; r < 4; ++r){
    float v0 = val[qt][0][r], v1 = val[qt][1][r];
    float p1 = rsum16(v0 + v1);
    float p2 = rsum16(v0*v0 + v1*v1);
    if (c == 0){
      int rr = qt*16 + g*4 + r;
      sm1[rr][w] = p1; sm2[rr][w] = p2;
    }
  }
  __syncthreads();  // #1

  float yv[2][2][4];   // LN1 output, kept as LN2 residual
  #pragma unroll
  for (int qt = 0; qt < 2; ++qt)
  #pragma unroll
  for (int r = 0; r < 4; ++r){
    int rr = qt*16 + g*4 + r;
    float S1 = 0.f, S2 = 0.f;
    #pragma unroll
    for (int j = 0; j < 8; ++j){ S1 += sm1[rr][j]; S2 += sm2[rr][j]; }
    float mean = S1 * (1.0f/256.0f);
    float var  = S2 * (1.0f/256.0f) - mean*mean;
    float rstd = rsqrtf(var + 1e-5f);
    #pragma unroll
    for (int nt = 0; nt < 2; ++nt){
      int col = n0 + nt*16 + c;
      float y = (val[qt][nt][r] - mean) * rstd * g1[col] + be1[col];
      yv[qt][nt][r] = y;
      int elem = rr*256 + col;
      x1t[elem ^ ((rr & 7) << 3)] = f2bf(y);
    }
  }
  __syncthreads();  // #2: x1t visible

  f32x4 acc3[2][2];
  #pragma unroll
  for (int i = 0; i < 2; ++i)
    #pragma unroll
    for (int j = 0; j < 2; ++j){ f32x4 z = {0.f,0.f,0.f,0.f}; acc3[i][j] = z; }

  #pragma unroll
  for (int half = 0; half < 2; ++half){
    // ---- phase B: FFN1 for cols [half*512, half*512+512) + LeakyReLU -> ht ----
    #pragma unroll
    for (int ns = 0; ns < 2; ++ns){
      const int ncol = half*512 + w*64 + ns*32;   // global h col base
      f32x4 acc2[2][2];
      #pragma unroll
      for (int i = 0; i < 2; ++i)
        #pragma unroll
        for (int j = 0; j < 2; ++j){ f32x4 z = {0.f,0.f,0.f,0.f}; acc2[i][j] = z; }
      #pragma unroll
      for (int kt = 0; kt < 8; ++kt){
        int e0 = (     c)*256 + kt*32 + g*8;
        int e1 = (16 + c)*256 + kt*32 + g*8;
        bf16x8 a0 = lds_bf8(x1t + (e0 ^ ((c & 7) << 3)));
        bf16x8 a1 = lds_bf8(x1t + (e1 ^ (((16 + c) & 7) << 3)));
        bf16x8 b0 = ld_bf8(W1 + (size_t)(ncol +      c) * 256 + kt*32 + g*8);
        bf16x8 b1v= ld_bf8(W1 + (size_t)(ncol + 16 + c) * 256 + kt*32 + g*8);
        acc2[0][0] = MFMA(a0, b0, acc2[0][0]);
        acc2[0][1] = MFMA(a0, b1v, acc2[0][1]);
        acc2[1][0] = MFMA(a1, b0, acc2[1][0]);
        acc2[1][1] = MFMA(a1, b1v, acc2[1][1]);
      }
      #pragma unroll
      for (int qt = 0; qt < 2; ++qt)
      #pragma unroll
      for (int nt = 0; nt < 2; ++nt)
      #pragma unroll
      for (int r = 0; r < 4; ++r){
        int row = qt*16 + g*4 + r;
        int gcol = ncol + nt*16 + c;
        float v = acc2[qt][nt][r] + b1[gcol];
        v = (v >= 0.f) ? v : v * 0.01f;
        int elem = row*512 + (gcol - half*512);
        ht[elem ^ ((row & 7) << 3)] = f2bf(v);
      }
    }
    __syncthreads();  // ht ready

    // ---- phase C: FFN2 partial K (512 cols of this half) ----
    #pragma unroll
    for (int kt = 0; kt < 16; ++kt){
      int e0 = (     c)*512 + kt*32 + g*8;
      int e1 = (16 + c)*512 + kt*32 + g*8;
      bf16x8 a0 = lds_bf8(ht + (e0 ^ ((c & 7) << 3)));
      bf16x8 a1 = lds_bf8(ht + (e1 ^ (((16 + c) & 7) << 3)));
      int kg = half*512 + kt*32 + g*8;
      bf16x8 b0 = ld_bf8(W2 + (size_t)(n0 +      c) * 1024 + kg);
      bf16x8 b1v= ld_bf8(W2 + (size_t)(n0 + 16 + c) * 1024 + kg);
      acc3[0][0] = MFMA(a0, b0, acc3[0][0]);
      acc3[0][1] = MFMA(a0, b1v, acc3[0][1]);
      acc3[1][0] = MFMA(a1, b0, acc3[1][0]);
      acc3[1][1] = MFMA(a1, b1v, acc3[1][1]);
    }
    __syncthreads();  // before ht overwrite
  }

  // ---- LN2 epilogue ----
  float val3[2][2][4];
  #pragma unroll
  for (int qt = 0; qt < 2; ++qt)
  #pragma unroll
  for (int nt = 0; nt < 2; ++nt)
  #pragma unroll
  for (int r = 0; r < 4; ++r){
    int col = n0 + nt*16 + c;
    val3[qt][nt][r] = acc3[qt][nt][r] + b2[col] + yv[qt][nt][r];
  }

  #pragma unroll
  for (int qt = 0; qt < 2; ++qt)
  #pragma unroll
  for (int r = 0; r < 4; ++r){
    float v0 = val3[qt][0][r], v1 = val3[qt][1][r];
    float p1 = rsum16(v0 + v1);
    float p2 = rsum16(v0*v0 + v1*v1);
    if (c == 0){
      int rr = qt*16 + g*4 + r;
      sm1[rr][w] = p1; sm2[rr][w] = p2;
    }
  }
  __syncthreads();

  #pragma unroll
  for (int qt = 0; qt < 2; ++qt)
  #pragma unroll
  for (int r = 0; r < 4; ++r){
    int rr = qt*16 + g*4 + r;
    float S1 = 0.f, S2 = 0.f;
    #pragma unroll
    for (int j = 0; j < 8; ++j){ S1 += sm1[rr][j]; S2 += sm2[rr][j]; }
    float mean = S1 * (1.0f/256.0f);
    float var  = S2 * (1.0f/256.0f) - mean*mean;
    float rstd = rsqrtf(var + 1e-5f);
    int mrow = m0 + rr;
    #pragma unroll
    for (int nt = 0; nt < 2; ++nt){
      int col = n0 + nt*16 + c;
      out[(size_t)mrow*256 + col] = (val3[qt][nt][r] - mean) * rstd * g2[col] + be2[col];
    }
  }
}

// ---------------- launcher ----------------------------------------------------
extern "C" void kernel_launch(void* const* d_in, const int* in_sizes, int n_in,
                              void* d_out, int out_size, void* d_ws, size_t ws_size,
                              hipStream_t stream)
{
  (void)in_sizes; (void)n_in; (void)out_size; (void)ws_size;
  const float* x   = (const float*)d_in[0];
  const float* pos = (const float*)d_in[1];
  const float* pad = (const float*)d_in[2];
  const float* Wq  = (const float*)d_in[3];
  const float* bq  = (const float*)d_in[4];
  const float* Wk  = (const float*)d_in[5];
  const float* bk  = (const float*)d_in[6];
  const float* Wv  = (const float*)d_in[7];
  const float* bv  = (const float*)d_in[8];
  const float* Wo  = (const float*)d_in[9];
  const float* bo  = (const float*)d_in[10];
  const float* W1  = (const float*)d_in[11];
  const float* b1  = (const float*)d_in[12];
  const float* W2  = (const float*)d_in[13];
  const float* b2  = (const float*)d_in[14];
  const float* g1  = (const float*)d_in[15];
  const float* be1 = (const float*)d_in[16];
  const float* g2  = (const float*)d_in[17];
  const float* be2 = (const float*)d_in[18];

  char* ws = (char*)d_ws;
  u16* wsX  = (u16*)(ws + OFF_X);
  u16* wsW3 = (u16*)(ws + OFF_WQ);
  u16* wsWo = (u16*)(ws + OFF_WO);
  u16* wsW1 = (u16*)(ws + OFF_W1);
  u16* wsW2 = (u16*)(ws + OFF_W2);
  u16* Qb   = (u16*)(ws + OFF_Q);
  u16* Kb   = (u16*)(ws + OFF_K);
  u16* VTb  = (u16*)(ws + OFF_VT);
  u16* ctx  = (u16*)(ws + OFF_CTX);

  prep_kernel<<<2816, 256, 0, stream>>>(x, Wq, Wk, Wv, Wo, W1, W2, wsX);
  qkv_kernel<<<dim3(256, 3), 512, 0, stream>>>(wsX, wsW3, bq, bk, bv, Qb, Kb, VTb);
  attn_kernel<<<512, 512, 0, stream>>>(pos, pad, Qb, Kb, VTb, ctx);
  tail_kernel<<<256, 512, 0, stream>>>(ctx, wsWo, bo, x, g1, be1,
                                       wsW1, b1, wsW2, b2, g2, be2, (float*)d_out);
}